// Round 8
// baseline (136.618 us; speedup 1.0000x reference)
//
#include <hip/hip_runtime.h>
#include <math.h>

// Problem constants
constexpr int Bn = 32;
constexpr int Cn = 512;
constexpr int Tn = 1024;
constexpr int KS = 13;

// Tiling (r9 chassis: best measured 43.4us rocprof / 127.6 bench)
constexpr int CB   = 32;           // channels per block -> 512 blocks, 2 blocks/CU
constexpr int TT   = 64;           // timesteps per chunk
constexpr int NCH  = Tn / TT;      // 16 chunks
constexpr int DSTR = TT + 1;       // 65: bank (65c+j)%32 = (c+j)%32 -> conflict-free
constexpr int NCW  = 4;            // conv waves
constexpr int SEG  = CB / NCW;     // 8 output rows per conv thread
constexpr int NL   = SEG + KS - 1; // 20 input rows per conv thread
constexpr int SRB  = 8;            // Sb ring depth (4-chunk store lag + safety)

// ---------------------------------------------------------------------------
// r17 = r9 + WIDE STORES (single change, clean attribution).
// Evidence: every structure this session (spin r8, barrier r9, 4blk r10,
// fat-period r14, zero-barrier r15, 2xTLP r16) caps at 2.1-2.6 TB/s combined
// HBM traffic; r9 (best) = 2.5 TB/s. All I/O moves in 256B granules strided
// 4KB (64-float row segments). Theory: DRAM efficiency at 256B scattered
// granules caps effective BW ~2.5 TB/s; write-buffer backpressure on the
// 65.5MB of stores (never L3-absorbed) convoys the barrier group -> the
// structure-independent ~45us wall and flat VALUBusy 27-40%.
// Fix: store wave defers 4 chunks, then writes each channel's 256-t span as
// ONE dwordx4 wave-instruction = 1KB contiguous (64 lanes x 16B). 4x fewer
// store instrs, 4x wider DRAM granules. Spike masks: 8-deep uint2 ring in
// LDS (also fixes r9's latent scan/store dbuf race -- store(k-1) and
// scan(k+1) shared a slot in the same window; ring slots rewrite at
// B(4g+8) > store window end B(4g+5), safe by construction).
// Everything else byte-identical to r9: conv register ring, scan math,
// 17 barriers per role, no vmcnt drains anywhere.
// Math (kw double-exp emulation, ascending no-FMA conv, scan op order) is
// bit-identical to the validated r2..r9 kernels (absmax 0.0).
// ---------------------------------------------------------------------------

__device__ __forceinline__ void wg_barrier() {
  asm volatile("" ::: "memory");
  __builtin_amdgcn_s_barrier();
  asm volatile("" ::: "memory");
}
__device__ __forceinline__ void lds_fence() {
  asm volatile("s_waitcnt lgkmcnt(0)" ::: "memory");
}

#define SCAN16(DV, TB)                                                   \
  _Pragma("unroll")                                                      \
  for (int j = 0; j < 16; ++j) {                                         \
    const float rthr = (mem > 0.5f) ? 0.5f : 0.0f;  /* reset: OLD mem */ \
    float a_  = __fmul_rn(0.95f, mem);                                   \
    float s2_ = __fadd_rn(a_, DV[j]);                                    \
    mem = __fsub_rn(s2_, rthr);                                          \
    const unsigned int bit = (mem > 0.5f) ? 1u : 0u;                     \
    if ((TB) + j < 32) lo |= bit << ((TB) + j);                          \
    else               hi |= bit << ((TB) + j - 32);                     \
  }

__global__ __launch_bounds__(384, 3)
void snn_fused(const float* __restrict__ x, const float* __restrict__ wp,
               float* __restrict__ out) {
  __shared__ float DA[CB][DSTR];             // drive double buffer (16.6 KB)
  __shared__ float DB[CB][DSTR];
  __shared__ __align__(8) uint2 Sb[SRB][CB + 1]; // spike ring, +1 pad: the
  // store-side ds_read banks (66s+2c+h)%32 = (2s+2c+h)%32 are distinct per
  // slot -> conflict-free 8-way-broadcast read groups.

  const int tid = threadIdx.x;
  const int b   = blockIdx.y;
  const int c0  = blockIdx.x * CB;
  const long xbase = (long)b * Cn * Tn;

  // ---- Gaussian weights, numpy float32 bit-emulation (validated) ----
  float kw[KS];
  {
    float w  = wp[0];
    float wc = fminf(fmaxf(w, 1.0f), 10.0f);      // clip(w, 1, 10)
    float sigma = __fadd_rn(5.5f, wc);
    float e[KS];
#pragma unroll
    for (int i = 0; i < KS; ++i) {
      float q = __fdiv_rn((float)(i - 6), sigma);
      float t = __fmul_rn(-0.5f, __fmul_rn(q, q));
      e[i] = (float)exp((double)t);
    }
    // numpy pairwise_sum order for n=13
    float s = __fadd_rn(
        __fadd_rn(__fadd_rn(e[0], e[1]), __fadd_rn(e[2], e[3])),
        __fadd_rn(__fadd_rn(e[4], e[5]), __fadd_rn(e[6], e[7])));
    s = __fadd_rn(s, e[8]);  s = __fadd_rn(s, e[9]);  s = __fadd_rn(s, e[10]);
    s = __fadd_rn(s, e[11]); s = __fadd_rn(s, e[12]);
#pragma unroll
    for (int i = 0; i < KS; ++i) kw[i] = __fdiv_rn(e[i], s);
  }

  if (tid < 64) {
    // ======================= scan wave (lanes >= CB masked) =============
    const int c = tid;
    float mem = 0.0f;
    wg_barrier();                              // B0: D(0) published
    for (int k = 0; k < NCH; ++k) {
      if (c < CB) {
        const float* Dc = (k & 1) ? &DB[c][0] : &DA[c][0];
        unsigned int lo = 0u, hi = 0u;
        float dvA[16], dvB[16];                // named arrays, const idx only
#pragma unroll
        for (int j = 0; j < 16; ++j) dvA[j] = Dc[j];
#pragma unroll
        for (int j = 0; j < 16; ++j) dvB[j] = Dc[16 + j];   // lookahead g=1
        SCAN16(dvA, 0)
#pragma unroll
        for (int j = 0; j < 16; ++j) dvA[j] = Dc[32 + j];   // lookahead g=2
        SCAN16(dvB, 16)
#pragma unroll
        for (int j = 0; j < 16; ++j) dvB[j] = Dc[48 + j];   // lookahead g=3
        SCAN16(dvA, 32)
        SCAN16(dvB, 48)
        Sb[k & (SRB - 1)][c] = make_uint2(lo, hi);
      }
      lds_fence();                             // reads+Sb write retired
      wg_barrier();                            // B(k+1)
    }
  } else if (tid < 64 + 64 * NCW) {
    // ====== conv waves (register-ring producers, loads + LDS writes) ====
    const int ctid = tid - 64;
    const int col  = ctid & 63;                // t-column (lane)
    const int segS = (ctid >> 6) * SEG;        // 0,8,16,24
    const int cin0 = c0 + segS - 6;

    float xA[NL], xB[NL], xC[NL];              // 3-buffer rotation (named)

    auto load_chunk = [&](int m, float* dst) {
#pragma unroll
      for (int j = 0; j < NL; ++j) {
        const int gc = cin0 + j;
        float v = 0.0f;
        if (gc >= 0 && gc < Cn)                // zero pad; per-wave uniform
          v = x[xbase + (long)gc * Tn + m * TT + col];
        dst[j] = v;
      }
    };
    auto conv_chunk = [&](const float* xs, float (*D)[DSTR]) {
#pragma unroll
      for (int r = 0; r < SEG; ++r) {
        float acc = __fmul_rn(kw[0], xs[r]);   // ascending, no FMA
#pragma unroll
        for (int i = 1; i < KS; ++i)
          acc = __fadd_rn(acc, __fmul_rn(kw[i], xs[r + i]));
        D[segS + r][col] = __fsub_rn(xs[r + 6], acc);  // x - x_mean
      }
    };

    // prologue: fill ring, publish D(0)
    load_chunk(0, xA);
    load_chunk(1, xB);
    load_chunk(2, xC);
    conv_chunk(xA, DA);                        // chunk 0 -> DA (waits xA only)
    lds_fence();
    wg_barrier();                              // B0

    // STEP(K): issue loads K+3 (distance-2), conv chunk K+1 from the buffer
    // loaded two iterations ago, lgkm, barrier. No vmcnt drain anywhere.
#define STEPC(K, BL, BC)                                                 \
    do {                                                                 \
      if ((K) + 3 < NCH) load_chunk((K) + 3, BL);                        \
      conv_chunk(BC, (((K) + 1) & 1) ? DB : DA);                         \
      lds_fence();                                                       \
      wg_barrier();                                                      \
    } while (0)

    for (int kb = 0; kb < NCH - 1; kb += 3) {  // kb=0,3,6,9,12 -> K=0..14
      STEPC(kb + 0, xA, xB);
      STEPC(kb + 1, xB, xC);
      STEPC(kb + 2, xC, xA);
    }
#undef STEPC
    wg_barrier();                              // B16 (iter 15: no conv work)
  } else {
    // ====== store wave: 4-chunk groups, 1KB-contiguous dwordx4 stores =====
    // Lane L owns t = 4L..4L+3 of a 256-t group: chunk j = L>>4,
    // word half = (L>>3)&1, bit offset 4*(L&7). One wave-store per channel
    // = 64 lanes x 16B = 1KB contiguous (vs r9's 4x 256B granules).
    const int L     = tid & 63;
    const int slot0 = L >> 4;                  // chunk within group
    const int half  = (L >> 3) & 1;            // lo/hi word of uint2
    const unsigned sh = 4u * (unsigned)(L & 7);
    wg_barrier();                              // B0
    for (int k = 0; k < NCH; ++k) {
      wg_barrier();                            // B(k+1): Sb(k) published
      if ((k & 3) == 3) {
        const int g = k >> 2;                  // chunks 4g..4g+3 all published
        const long tbase = xbase + (long)c0 * Tn + (long)g * (4 * TT) + 4 * L;
#pragma unroll 4
        for (int c = 0; c < CB; ++c) {
          const uint2 pr = Sb[(4 * g + slot0) & (SRB - 1)][c];
          const unsigned wsrc = half ? pr.y : pr.x;    // LDS broadcast groups
          const unsigned nib  = wsrc >> sh;
          float4 o;
          o.x = (nib & 1u) ? 1.0f : 0.0f;
          o.y = (nib & 2u) ? 1.0f : 0.0f;
          o.z = (nib & 4u) ? 1.0f : 0.0f;
          o.w = (nib & 8u) ? 1.0f : 0.0f;
          *(float4*)&out[tbase + (long)c * Tn] = o;    // fire & forget, 16B
        }
      }
    }
    // group 3 (k=15) stored inside the loop after B16 -- no extra barrier;
    // kernel-end drains the stores.
  }
}

extern "C" void kernel_launch(void* const* d_in, const int* in_sizes, int n_in,
                              void* d_out, int out_size, void* d_ws, size_t ws_size,
                              hipStream_t stream) {
  const float* x  = (const float*)d_in[0];
  const float* w  = (const float*)d_in[1];
  float* out      = (float*)d_out;
  dim3 grid(Cn / CB, Bn, 1);
  snn_fused<<<grid, 384, 0, stream>>>(x, w, out);
}

// Round 9
// 128.462 us; speedup vs baseline: 1.0635x; 1.0635x over previous
//
#include <hip/hip_runtime.h>
#include <math.h>

// Problem constants
constexpr int Bn = 32;
constexpr int Cn = 512;
constexpr int Tn = 1024;
constexpr int KS = 13;

// Tiling
constexpr int CB   = 64;           // channels per block -> 256 blocks, 1 block/CU
constexpr int TT   = 64;           // timesteps per chunk
constexpr int NCH  = Tn / TT;      // 16 chunks
constexpr int DSTR = TT + 1;       // 65: scan bank (65c+j)%32=(c+j)%32 -> 2-way worst = free
constexpr int NCW  = 8;            // conv waves (SEG=8 keeps the VGPR-safe 20-float ring)
constexpr int SEG  = CB / NCW;     // 8 output rows per conv thread
constexpr int NL   = SEG + KS - 1; // 20 input rows per conv thread
constexpr int SRB  = 8;            // Sb ring depth (race-free by construction)

// ---------------------------------------------------------------------------
// r18: ISSUE-MINIMIZATION. Evidence across r8-r17: VALUBusy pinned 27-41%
// regardless of waves/SIMD (1,2,3), barriers or none -> stalls are not
// latency-maskable; duration tracks TOTAL ISSUED INSTRUCTIONS per CU
// (r16: 2x scan redundancy -> +58% dur at flat busy; r8 1blk/CU == r9
// 2blk/CU at equal per-CU instr; r14 spill -> +49%). So: cut instructions.
// r9 wasted half the scan + store wave issue on exec-masked lanes (CB=32 on
// 64-lane waves). CB=64 + full-lane scan halves scan/store issue per channel
// (conv + load issue per channel unchanged: NL/SEG is CB-independent).
// Block: 1 scan(64ch) + 8 conv(NL=20 ring, ~64 VGPR like r9) + 1 store
// = 640 threads; 256 blocks = 1/CU. r17's burst store REGRESSED -> back to
// r9-style per-chunk streaming stores. Sb 8-ring kept (fixes r9's latent
// scan/store slot race). 17-barrier schedule identical to r17 (verified):
// conv STEPC(K) in (B(K),B(K+1)) writes D[(K+1)&1]; scan(k) in
// (B(k),B(k+1)) reads D[k&1], writes Sb[k&7]; store(k) in (B(k+1),B(k+2))
// reads Sb[k&7], rewritten first at scan(k+8) in (B(k+8),B(k+9)) -> safe.
// Math (kw double-exp emulation, ascending no-FMA conv, scan op order) is
// bit-identical to the validated r2..r17 kernels (absmax 0.0).
// ---------------------------------------------------------------------------

__device__ __forceinline__ void wg_barrier() {
  asm volatile("" ::: "memory");
  __builtin_amdgcn_s_barrier();
  asm volatile("" ::: "memory");
}
__device__ __forceinline__ void lds_fence() {
  asm volatile("s_waitcnt lgkmcnt(0)" ::: "memory");
}

#define SCAN16(DV, TB)                                                   \
  _Pragma("unroll")                                                      \
  for (int j = 0; j < 16; ++j) {                                         \
    const float rthr = (mem > 0.5f) ? 0.5f : 0.0f;  /* reset: OLD mem */ \
    float a_  = __fmul_rn(0.95f, mem);                                   \
    float s2_ = __fadd_rn(a_, DV[j]);                                    \
    mem = __fsub_rn(s2_, rthr);                                          \
    const unsigned int bit = (mem > 0.5f) ? 1u : 0u;                     \
    if ((TB) + j < 32) lo |= bit << ((TB) + j);                          \
    else               hi |= bit << ((TB) + j - 32);                     \
  }

__global__ __launch_bounds__(640, 2)
void snn_fused(const float* __restrict__ x, const float* __restrict__ wp,
               float* __restrict__ out) {
  __shared__ float DA[CB][DSTR];             // drive double buffer (33.3 KB)
  __shared__ float DB[CB][DSTR];
  __shared__ __align__(8) uint2 Sb[SRB][CB + 1]; // spike ring (4.2 KB), +1 pad

  const int tid = threadIdx.x;
  const int b   = blockIdx.y;
  const int c0  = blockIdx.x * CB;
  const long xbase = (long)b * Cn * Tn;

  // ---- Gaussian weights, numpy float32 bit-emulation (validated) ----
  float kw[KS];
  {
    float w  = wp[0];
    float wc = fminf(fmaxf(w, 1.0f), 10.0f);      // clip(w, 1, 10)
    float sigma = __fadd_rn(5.5f, wc);
    float e[KS];
#pragma unroll
    for (int i = 0; i < KS; ++i) {
      float q = __fdiv_rn((float)(i - 6), sigma);
      float t = __fmul_rn(-0.5f, __fmul_rn(q, q));
      e[i] = (float)exp((double)t);
    }
    // numpy pairwise_sum order for n=13
    float s = __fadd_rn(
        __fadd_rn(__fadd_rn(e[0], e[1]), __fadd_rn(e[2], e[3])),
        __fadd_rn(__fadd_rn(e[4], e[5]), __fadd_rn(e[6], e[7])));
    s = __fadd_rn(s, e[8]);  s = __fadd_rn(s, e[9]);  s = __fadd_rn(s, e[10]);
    s = __fadd_rn(s, e[11]); s = __fadd_rn(s, e[12]);
#pragma unroll
    for (int i = 0; i < KS; ++i) kw[i] = __fdiv_rn(e[i], s);
  }

  if (tid < 64) {
    // ============ scan wave: ALL 64 lanes active (lane = channel) ========
    const int c = tid;
    float mem = 0.0f;
    wg_barrier();                              // B0: D(0) published
    for (int k = 0; k < NCH; ++k) {
      const float* Dc = (k & 1) ? &DB[c][0] : &DA[c][0];
      unsigned int lo = 0u, hi = 0u;
      float dvA[16], dvB[16];                  // named arrays, const idx only
#pragma unroll
      for (int j = 0; j < 16; ++j) dvA[j] = Dc[j];
#pragma unroll
      for (int j = 0; j < 16; ++j) dvB[j] = Dc[16 + j];   // lookahead g=1
      SCAN16(dvA, 0)
#pragma unroll
      for (int j = 0; j < 16; ++j) dvA[j] = Dc[32 + j];   // lookahead g=2
      SCAN16(dvB, 16)
#pragma unroll
      for (int j = 0; j < 16; ++j) dvB[j] = Dc[48 + j];   // lookahead g=3
      SCAN16(dvA, 32)
      SCAN16(dvB, 48)
      Sb[k & (SRB - 1)][c] = make_uint2(lo, hi);
      lds_fence();                             // reads + Sb write retired
      wg_barrier();                            // B(k+1)
    }
  } else if (tid < 64 + 64 * NCW) {
    // ====== conv waves (register-ring producers, loads + LDS writes) ====
    const int ctid = tid - 64;
    const int col  = ctid & 63;                // t-column (lane)
    const int segS = (ctid >> 6) * SEG;        // 0,8,...,56
    const int cin0 = c0 + segS - 6;

    float xA[NL], xB[NL], xC[NL];              // 3-buffer rotation (named)

    auto load_chunk = [&](int m, float* dst) {
#pragma unroll
      for (int j = 0; j < NL; ++j) {
        const int gc = cin0 + j;
        float v = 0.0f;
        if (gc >= 0 && gc < Cn)                // zero pad; per-wave uniform
          v = x[xbase + (long)gc * Tn + m * TT + col];
        dst[j] = v;
      }
    };
    auto conv_chunk = [&](const float* xs, float (*D)[DSTR]) {
#pragma unroll
      for (int r = 0; r < SEG; ++r) {
        float acc = __fmul_rn(kw[0], xs[r]);   // ascending, no FMA
#pragma unroll
        for (int i = 1; i < KS; ++i)
          acc = __fadd_rn(acc, __fmul_rn(kw[i], xs[r + i]));
        D[segS + r][col] = __fsub_rn(xs[r + 6], acc);  // x - x_mean
      }
    };

    // prologue: fill ring, publish D(0)
    load_chunk(0, xA);
    load_chunk(1, xB);
    load_chunk(2, xC);
    conv_chunk(xA, DA);                        // chunk 0 -> DA (waits xA only)
    lds_fence();
    wg_barrier();                              // B0

    // STEPC(K): issue loads K+3 (distance-2), conv chunk K+1 from the buffer
    // loaded two iterations ago, lgkm, barrier. No vmcnt drain anywhere.
#define STEPC(K, BL, BC)                                                 \
    do {                                                                 \
      if ((K) + 3 < NCH) load_chunk((K) + 3, BL);                        \
      conv_chunk(BC, (((K) + 1) & 1) ? DB : DA);                         \
      lds_fence();                                                       \
      wg_barrier();                                                      \
    } while (0)

    for (int kb = 0; kb < NCH - 1; kb += 3) {  // kb=0,3,6,9,12 -> K=0..14
      STEPC(kb + 0, xA, xB);
      STEPC(kb + 1, xB, xC);
      STEPC(kb + 2, xC, xA);
    }
#undef STEPC
    wg_barrier();                              // B16 (iter 15: no conv work)
  } else {
    // ====== store wave (LDS broadcast reads + streaming dword stores) ===
    const int L = tid & 63;                    // t-column (lane)
    wg_barrier();                              // B0
    for (int k = 0; k < NCH; ++k) {
      wg_barrier();                            // B(k+1): Sb(k) published
      const uint2* Sp = Sb[k & (SRB - 1)];
      const long obase = xbase + (long)c0 * Tn + (long)k * TT + L;
#pragma unroll 8
      for (int r = 0; r < CB; ++r) {
        const uint2 wb = Sp[r];                // ds_read_b64 broadcast
        const unsigned ws = (L & 32) ? wb.y : wb.x;
        out[obase + (long)r * Tn] =
            ((ws >> (L & 31)) & 1u) ? 1.0f : 0.0f;       // fire & forget
      }
    }
  }
}

extern "C" void kernel_launch(void* const* d_in, const int* in_sizes, int n_in,
                              void* d_out, int out_size, void* d_ws, size_t ws_size,
                              hipStream_t stream) {
  const float* x  = (const float*)d_in[0];
  const float* w  = (const float*)d_in[1];
  float* out      = (float*)d_out;
  dim3 grid(Cn / CB, Bn, 1);                   // 8 x 32 = 256 blocks
  snn_fused<<<grid, 64 + 64 * NCW + 64, 0, stream>>>(x, w, out);
}